// Round 14
// baseline (394.680 us; speedup 1.0000x reference)
//
#include <hip/hip_runtime.h>
#include <stdint.h>

typedef __attribute__((ext_vector_type(8))) short short8;
typedef __attribute__((ext_vector_type(4))) float f32x4;

__device__ __forceinline__ unsigned short f2bf(float f) {
    unsigned u = __float_as_uint(f);
    unsigned r = u + 0x7fffu + ((u >> 16) & 1u);   // RNE
    return (unsigned short)(r >> 16);
}
// monotone float<->uint encoding for atomicMax on floats
__device__ __forceinline__ unsigned fenc(float f) {
    unsigned u = __float_as_uint(f);
    return (u & 0x80000000u) ? ~u : (u | 0x80000000u);
}
__device__ __forceinline__ float fdec(unsigned e) {
    unsigned u = (e & 0x80000000u) ? (e & 0x7fffffffu) : ~e;
    return __uint_as_float(u);
}

// ---- x -> running fp32 x in d_out; W -> bf16 W^T; init s2 max slots ---------
__global__ __launch_bounds__(256) void k_init(const float* __restrict__ xin,
                                              const float* __restrict__ Wf,
                                              float* __restrict__ xq,
                                              unsigned short* __restrict__ wTb,
                                              unsigned* __restrict__ s2mx) {
    int blk = blockIdx.x, tid = threadIdx.x;
    if (blk < 2048) {
        int e0 = (blk * 256 + tid) * 4;
        *(f32x4*)(xq + e0) = *(const f32x4*)(xin + e0);
    } else if (blk < 2240) {
        int c = (blk - 2048) * 256 + tid;            // < 49152
        int l = c >> 14, rem = c & 16383, n = rem >> 7, k = rem & 127;
        wTb[c] = f2bf(Wf[l * 16384 + k * 128 + n]);  // wTb[l][n][k] = W[l][k][n]
    } else if (tid < 24) {
        s2mx[tid] = fenc(-3e38f);
    }
}

// ---- pack adj (int 0/1) to 64-bit masks: packed[row*32+wd] bit l = adj[row][wd*64+l]
__global__ __launch_bounds__(256) void k_pack(const int* __restrict__ adj,
                                              unsigned long long* __restrict__ packed) {
    int w = (blockIdx.x * 256 + threadIdx.x) >> 6;   // global wave id, 8192 waves
    int lane = threadIdx.x & 63;
    for (int k = 0; k < 64; k++) {
        int q = w * 64 + k;                           // word index 0..524287
        int row = q >> 5, wd = q & 31;
        int v = adj[row * 2048 + wd * 64 + lane];
        unsigned long long m = __ballot(v > 0);
        if (lane == 0) packed[q] = m;
    }
}

// ---- per layer: h = relu(x@W+b) via bf16 MFMA; s1,s2; batch max; H^T bf16 ---
__global__ __launch_bounds__(256) void k_h(
    const float* __restrict__ xq, const unsigned short* __restrict__ wTb,
    const float* __restrict__ bF, const float* __restrict__ aF, int layer,
    unsigned short* __restrict__ hT, float* __restrict__ s1g,
    float* __restrict__ s2g, unsigned* __restrict__ s2mx)
{
    __shared__ short xs[64 * 136];    // 17.4 KB, x tile bf16
    __shared__ short wsb[128 * 136];  // 34.8 KB, W^T tile bf16; reused for transpose
    __shared__ float s2blk[4];
    int blk = blockIdx.x, tid = threadIdx.x;
    int row0 = blk * 64, b = blk >> 5;
    int w = tid >> 6, lane = tid & 63, quad = lane >> 4, l15 = lane & 15;

    for (int c = tid; c < 1024; c += 256) {           // x: 64 rows x 128 k
        int r = c >> 4, kg = c & 15;
        const float* src = &xq[(row0 + r) * 128 + kg * 8];
        f32x4 v0 = *(const f32x4*)src;
        f32x4 v1 = *(const f32x4*)(src + 4);
        short8 o;
        o[0] = (short)f2bf(v0[0]); o[1] = (short)f2bf(v0[1]);
        o[2] = (short)f2bf(v0[2]); o[3] = (short)f2bf(v0[3]);
        o[4] = (short)f2bf(v1[0]); o[5] = (short)f2bf(v1[1]);
        o[6] = (short)f2bf(v1[2]); o[7] = (short)f2bf(v1[3]);
        *(short8*)&xs[r * 136 + kg * 8] = o;
    }
    const unsigned short* wl = wTb + layer * 16384;
    for (int c = tid; c < 2048; c += 256) {           // W^T: 128 n x 128 k
        int n = c >> 4, kg = c & 15;
        *(short8*)&wsb[n * 136 + kg * 8] = *(const short8*)&wl[n * 128 + kg * 8];
    }
    __syncthreads();

    f32x4 acc[8];
#pragma unroll
    for (int t = 0; t < 8; t++) acc[t] = {0.f, 0.f, 0.f, 0.f};
#pragma unroll
    for (int ks = 0; ks < 4; ks++) {
        short8 af = *(const short8*)&xs[(w * 16 + l15) * 136 + ks * 32 + quad * 8];
#pragma unroll
        for (int t = 0; t < 8; t++) {
            short8 bf = *(const short8*)&wsb[(t * 16 + l15) * 136 + ks * 32 + quad * 8];
            acc[t] = __builtin_amdgcn_mfma_f32_16x16x32_bf16(af, bf, acc[t], 0, 0, 0);
        }
    }

    // epilogue: bias+relu, s1/s2 row dots (reduce over l15 lanes via shfl)
    float s1p[4] = {0.f, 0.f, 0.f, 0.f}, s2p[4] = {0.f, 0.f, 0.f, 0.f};
#pragma unroll
    for (int t = 0; t < 8; t++) {
        int colg = t * 16 + l15;
        float bgf = bF[layer * 128 + colg];
        float a1 = aF[layer * 256 + colg];
        float a2 = aF[layer * 256 + 128 + colg];
#pragma unroll
        for (int r = 0; r < 4; r++) {
            float v = acc[t][r] + bgf;
            v = v > 0.f ? v : 0.f;
            acc[t][r] = v;
            s1p[r] = fmaf(v, a1, s1p[r]);
            s2p[r] = fmaf(v, a2, s2p[r]);
        }
    }
#pragma unroll
    for (int r = 0; r < 4; r++) {
#pragma unroll
        for (int off = 1; off < 16; off <<= 1) {
            s1p[r] += __shfl_xor(s1p[r], off, 64);
            s2p[r] += __shfl_xor(s2p[r], off, 64);
        }
    }
    if (l15 == 0) {
#pragma unroll
        for (int r = 0; r < 4; r++) {
            int rowg = row0 + w * 16 + quad * 4 + r;
            s1g[rowg] = s1p[r];
            s2g[rowg] = s2p[r];
        }
    }
    float mx = fmaxf(fmaxf(s2p[0], s2p[1]), fmaxf(s2p[2], s2p[3]));
    mx = fmaxf(mx, __shfl_xor(mx, 16, 64));
    mx = fmaxf(mx, __shfl_xor(mx, 32, 64));
    if (lane == 0) s2blk[w] = mx;
    __syncthreads();                  // all MFMA reads of wsb done; s2blk visible

    short* st = (short*)wsb;          // transpose buffer (64 x 130)
#pragma unroll
    for (int t = 0; t < 8; t++)
#pragma unroll
        for (int r = 0; r < 4; r++)
            st[(w * 16 + quad * 4 + r) * 130 + t * 16 + l15] = (short)f2bf(acc[t][r]);
    __syncthreads();
    if (tid == 0) {
        float m2 = fmaxf(fmaxf(s2blk[0], s2blk[1]), fmaxf(s2blk[2], s2blk[3]));
        atomicMax(&s2mx[layer * 8 + b], fenc(m2));
    }
    int i0 = (blk & 31) * 64;
    for (int c = tid; c < 1024; c += 256) {
        int d = c >> 3, ig = c & 7;
        short8 o;
#pragma unroll
        for (int ii = 0; ii < 8; ii++) o[ii] = st[(ig * 8 + ii) * 130 + d];
        *(short8*)&hT[(b * 128 + d) * 2048 + i0 + ig * 8] = o;
    }
}

// ---- per layer: flash P@H via MFMA, B-fragments direct from global (no LDS
// in the hot loop, no barriers). grid 512: 32-row blocks; wave w owns 8 jt. ---
__global__ __launch_bounds__(256) void k_attn(
    const unsigned long long* __restrict__ packed,
    const unsigned short* __restrict__ hT, const float* __restrict__ s1g,
    const float* __restrict__ s2g, const unsigned* __restrict__ s2mx,
    int layer, float* __restrict__ Opart, float* __restrict__ Ppart)
{
    __shared__ unsigned long long bits_t[32 * 32];   // 8 KB: [jt][row]
    int blk = blockIdx.x, tid = threadIdx.x;
    int b = blk >> 6;                                // 64 row-blocks per batch
    int rowg0 = blk * 32;
    int w = tid >> 6, lane = tid & 63, quad = lane >> 4, l15 = lane & 15;

    // stage bits transposed (coalesced on packed; conflict-free reads later)
    for (int c = tid; c < 1024; c += 256) {
        int r = c >> 5, jt = c & 31;
        bits_t[jt * 32 + r] = packed[(rowg0 + r) * 32 + jt];
    }

    float s2m = fdec(s2mx[layer * 8 + b]);
    float s1v[2], mhat[2];
#pragma unroll
    for (int s = 0; s < 2; s++) {
        s1v[s] = s1g[rowg0 + s * 16 + l15];
        float tmh = s1v[s] + s2m;
        mhat[s] = fmaxf(tmh, 0.2f * tmh);            // leaky(s1 + max_b s2) >= all e
    }
    f32x4 acc[2][9];
#pragma unroll
    for (int s = 0; s < 2; s++)
#pragma unroll
        for (int t = 0; t < 9; t++) acc[s][t] = {0.f, 0.f, 0.f, 0.f};

    // constant ones-column B fragment (column n=128 <-> t=8,l15==0)
    short8 onesf;
    {
        short one = (short)0x3F80;
        short v = (l15 == 0) ? one : (short)0;
        onesf[0]=v;onesf[1]=v;onesf[2]=v;onesf[3]=v;onesf[4]=v;onesf[5]=v;onesf[6]=v;onesf[7]=v;
    }
    __syncthreads();                                 // bits_t ready (only barrier)

    const float* s2b = s2g + b * 2048;
    const unsigned short* hTb = hT + (size_t)b * 128 * 2048;

    for (int jl = 0; jl < 8; jl++) {
        int jt = w * 8 + jl;                         // this wave's j-tile
        unsigned long long word0 = bits_t[jt * 32 + l15];
        unsigned long long word1 = bits_t[jt * 32 + 16 + l15];
#pragma unroll
        for (int ks = 0; ks < 2; ks++) {
            int jbase = jt * 64 + ks * 32 + quad * 8;
            short8 bfr[8];
#pragma unroll
            for (int t = 0; t < 8; t++)              // B direct from global (L2)
                bfr[t] = *(const short8*)&hTb[(t * 16 + l15) * 2048 + jbase];
            f32x4 sa = *(const f32x4*)&s2b[jbase];
            f32x4 sb = *(const f32x4*)&s2b[jbase + 4];
            float sv[8] = {sa[0], sa[1], sa[2], sa[3], sb[0], sb[1], sb[2], sb[3]};
#pragma unroll
            for (int s = 0; s < 2; s++) {
                unsigned long long word = s ? word1 : word0;
                unsigned b8 = (unsigned)(word >> (ks * 32 + quad * 8)) & 0xffu;
                short8 af;
#pragma unroll
                for (int jj = 0; jj < 8; jj++) {
                    float e = s1v[s] + sv[jj];
                    e = fmaxf(e, 0.2f * e);          // leaky_relu
                    float pvv = __expf(e - mhat[s]);
                    pvv = (b8 & (1u << jj)) ? pvv : 0.f;
                    af[jj] = (short)f2bf(pvv);
                }
#pragma unroll
                for (int t = 0; t < 8; t++)
                    acc[s][t] = __builtin_amdgcn_mfma_f32_16x16x32_bf16(af, bfr[t], acc[s][t], 0, 0, 0);
                acc[s][8] = __builtin_amdgcn_mfma_f32_16x16x32_bf16(af, onesf, acc[s][8], 0, 0, 0);
            }
        }
    }

    // each wave writes its j-slice partial O and psum (no reduction needed)
#pragma unroll
    for (int s = 0; s < 2; s++)
#pragma unroll
        for (int r = 0; r < 4; r++) {
            int rowgC = rowg0 + s * 16 + quad * 4 + r;
            // ones-tile row-sum lands only in column n=0 of tile 8 (l15==0):
            float psum = __shfl(acc[s][8][r], lane & 48, 64);
            if (l15 == 0) Ppart[w * 16384 + rowgC] = psum;
#pragma unroll
            for (int t = 0; t < 8; t++)
                Opart[((size_t)w * 16384 + rowgC) * 128 + t * 16 + l15] = acc[s][t][r];
        }
}

// ---- combine 4 wave-slices: x += (O0+O1+O2+O3) / (p0+p1+p2+p3) --------------
__global__ __launch_bounds__(256) void k_comb(
    const float* __restrict__ Opart, const float* __restrict__ Ppart,
    float* __restrict__ xq)
{
    int idx = blockIdx.x * 256 + threadIdx.x;    // f32x4 index, 524288 total
    int row = idx >> 5;                          // 32 f32x4 per row
    float p = Ppart[row] + Ppart[16384 + row] + Ppart[32768 + row] + Ppart[49152 + row];
    float rl = p > 0.f ? 1.0f / p : 0.f;
    // slices offset by 16384 rows * 128 = 2,097,152 floats
    f32x4 o0 = *(const f32x4*)&Opart[(size_t)idx * 4];
    f32x4 o1 = *(const f32x4*)&Opart[(size_t)idx * 4 + 2097152];
    f32x4 o2 = *(const f32x4*)&Opart[(size_t)idx * 4 + 4194304];
    f32x4 o3 = *(const f32x4*)&Opart[(size_t)idx * 4 + 6291456];
    f32x4 xv = *(const f32x4*)&xq[idx * 4];
#pragma unroll
    for (int k = 0; k < 4; k++) xv[k] += (o0[k] + o1[k] + o2[k] + o3[k]) * rl;
    *(f32x4*)&xq[idx * 4] = xv;
}

extern "C" void kernel_launch(void* const* d_in, const int* in_sizes, int n_in,
                              void* d_out, int out_size, void* d_ws, size_t ws_size,
                              hipStream_t stream) {
    // adj = largest input; among the rest (excluding x = d_in[0]): W > attn_a > bg
    const void* px = d_in[0];
    int ia = 1; long amax = -1;
    for (int i = 1; i < n_in; i++)
        if ((long)in_sizes[i] > amax) { amax = in_sizes[i]; ia = i; }
    int rem[8]; int m = 0;
    for (int i = 1; i < n_in && m < 8; i++) if (i != ia) rem[m++] = i;
    for (int i = 0; i < m; i++)
        for (int j = i + 1; j < m; j++)
            if (in_sizes[rem[j]] > in_sizes[rem[i]]) { int t = rem[i]; rem[i] = rem[j]; rem[j] = t; }
    const int*   padj = (const int*)((n_in > 1) ? d_in[ia] : d_in[0]);
    const float* pW = (const float*)((m > 0) ? d_in[rem[0]] : d_in[0]);
    const float* pa = (const float*)((m > 1) ? d_in[rem[1]] : d_in[0]);
    const float* pb = (const float*)((m > 2) ? d_in[rem[2]] : d_in[0]);

    float* xq = (float*)d_out;                        // running fp32 x = output
    char* ws = (char*)d_ws;
    unsigned long long* packed = (unsigned long long*)ws;   // 4 MiB bitmask
    unsigned short* hT = (unsigned short*)(ws + 4194304);   // 4 MiB bf16 H^T
    float* s1 = (float*)(ws + 8388608);                     // 64 KiB
    float* s2 = (float*)(ws + 8454144);                     // 64 KiB
    unsigned* s2mx = (unsigned*)(ws + 8519680);             // 24 slots
    unsigned short* wTb = (unsigned short*)(ws + 8519808);  // 96 KiB bf16 W^T
    float* Opart = (float*)(ws + 16777216);                 // 32 MiB (4 slices)
    float* Ppart = (float*)(ws + 50331648);                 // 256 KiB (4 slices)

    k_init<<<2241, 256, 0, stream>>>((const float*)px, pW, xq, wTb, s2mx);
    k_pack<<<2048, 256, 0, stream>>>(padj, packed);
    for (int l = 0; l < 3; l++) {
        k_h<<<256, 256, 0, stream>>>(xq, wTb, pb, pa, l, hT, s1, s2, s2mx);
        k_attn<<<512, 256, 0, stream>>>(packed, hT, s1, s2, s2mx, l, Opart, Ppart);
        k_comb<<<2048, 256, 0, stream>>>(Opart, Ppart, xq);
    }
}

// Round 15
// 363.367 us; speedup vs baseline: 1.0862x; 1.0862x over previous
//
#include <hip/hip_runtime.h>
#include <stdint.h>

typedef __attribute__((ext_vector_type(8))) short short8;
typedef __attribute__((ext_vector_type(4))) float f32x4;
typedef __attribute__((ext_vector_type(16))) float f32x16;
typedef __attribute__((ext_vector_type(4))) unsigned uint4v;

__device__ __forceinline__ unsigned short f2bf(float f) {
    unsigned u = __float_as_uint(f);
    unsigned r = u + 0x7fffu + ((u >> 16) & 1u);   // RNE
    return (unsigned short)(r >> 16);
}
// monotone float<->uint encoding for atomicMax on floats
__device__ __forceinline__ unsigned fenc(float f) {
    unsigned u = __float_as_uint(f);
    return (u & 0x80000000u) ? ~u : (u | 0x80000000u);
}
__device__ __forceinline__ float fdec(unsigned e) {
    unsigned u = (e & 0x80000000u) ? (e & 0x7fffffffu) : ~e;
    return __uint_as_float(u);
}

// ---- x -> running fp32 x in d_out; W -> bf16 W^T; init s2 max slots ---------
__global__ __launch_bounds__(256) void k_init(const float* __restrict__ xin,
                                              const float* __restrict__ Wf,
                                              float* __restrict__ xq,
                                              unsigned short* __restrict__ wTb,
                                              unsigned* __restrict__ s2mx) {
    int blk = blockIdx.x, tid = threadIdx.x;
    if (blk < 2048) {
        int e0 = (blk * 256 + tid) * 4;
        *(f32x4*)(xq + e0) = *(const f32x4*)(xin + e0);
    } else if (blk < 2240) {
        int c = (blk - 2048) * 256 + tid;            // < 49152
        int l = c >> 14, rem = c & 16383, n = rem >> 7, k = rem & 127;
        wTb[c] = f2bf(Wf[l * 16384 + k * 128 + n]);  // wTb[l][n][k] = W[l][k][n]
    } else if (tid < 24) {
        s2mx[tid] = fenc(-3e38f);
    }
}

// ---- pack adj (int 0/1) to 64-bit masks: packed[row*32+wd] bit l = adj[row][wd*64+l]
__global__ __launch_bounds__(256) void k_pack(const int* __restrict__ adj,
                                              unsigned long long* __restrict__ packed) {
    int w = (blockIdx.x * 256 + threadIdx.x) >> 6;   // global wave id, 8192 waves
    int lane = threadIdx.x & 63;
    for (int k = 0; k < 64; k++) {
        int q = w * 64 + k;                           // word index 0..524287
        int row = q >> 5, wd = q & 31;
        int v = adj[row * 2048 + wd * 64 + lane];
        unsigned long long m = __ballot(v > 0);
        if (lane == 0) packed[q] = m;
    }
}

// ---- per layer: h = relu(x@W+b) via bf16 MFMA; s1,s2; batch max; hP packed --
// hP[b][t][jt][lane][8]: element = h[j = jt*16 + (lane>>5)*8 + i][d = t*32 + (lane&31)]
__global__ __launch_bounds__(256) void k_h(
    const float* __restrict__ xq, const unsigned short* __restrict__ wTb,
    const float* __restrict__ bF, const float* __restrict__ aF, int layer,
    unsigned short* __restrict__ hP, float* __restrict__ s1g,
    float* __restrict__ s2g, unsigned* __restrict__ s2mx)
{
    __shared__ short xs[64 * 136];    // 17.4 KB, x tile bf16
    __shared__ short wsb[128 * 136];  // 34.8 KB, W^T tile bf16; reused for transpose
    __shared__ float s2blk[4];
    int blk = blockIdx.x, tid = threadIdx.x;
    int row0 = blk * 64, b = blk >> 5;
    int w = tid >> 6, lane = tid & 63, quad = lane >> 4, l15 = lane & 15;

    for (int c = tid; c < 1024; c += 256) {           // x: 64 rows x 128 k
        int r = c >> 4, kg = c & 15;
        const float* src = &xq[(row0 + r) * 128 + kg * 8];
        f32x4 v0 = *(const f32x4*)src;
        f32x4 v1 = *(const f32x4*)(src + 4);
        short8 o;
        o[0] = (short)f2bf(v0[0]); o[1] = (short)f2bf(v0[1]);
        o[2] = (short)f2bf(v0[2]); o[3] = (short)f2bf(v0[3]);
        o[4] = (short)f2bf(v1[0]); o[5] = (short)f2bf(v1[1]);
        o[6] = (short)f2bf(v1[2]); o[7] = (short)f2bf(v1[3]);
        *(short8*)&xs[r * 136 + kg * 8] = o;
    }
    const unsigned short* wl = wTb + layer * 16384;
    for (int c = tid; c < 2048; c += 256) {           // W^T: 128 n x 128 k
        int n = c >> 4, kg = c & 15;
        *(short8*)&wsb[n * 136 + kg * 8] = *(const short8*)&wl[n * 128 + kg * 8];
    }
    __syncthreads();

    f32x4 acc[8];
#pragma unroll
    for (int t = 0; t < 8; t++) acc[t] = {0.f, 0.f, 0.f, 0.f};
#pragma unroll
    for (int ks = 0; ks < 4; ks++) {
        short8 af = *(const short8*)&xs[(w * 16 + l15) * 136 + ks * 32 + quad * 8];
#pragma unroll
        for (int t = 0; t < 8; t++) {
            short8 bf = *(const short8*)&wsb[(t * 16 + l15) * 136 + ks * 32 + quad * 8];
            acc[t] = __builtin_amdgcn_mfma_f32_16x16x32_bf16(af, bf, acc[t], 0, 0, 0);
        }
    }

    // epilogue: bias+relu, s1/s2 row dots (reduce over l15 lanes via shfl)
    float s1p[4] = {0.f, 0.f, 0.f, 0.f}, s2p[4] = {0.f, 0.f, 0.f, 0.f};
#pragma unroll
    for (int t = 0; t < 8; t++) {
        int colg = t * 16 + l15;
        float bgf = bF[layer * 128 + colg];
        float a1 = aF[layer * 256 + colg];
        float a2 = aF[layer * 256 + 128 + colg];
#pragma unroll
        for (int r = 0; r < 4; r++) {
            float v = acc[t][r] + bgf;
            v = v > 0.f ? v : 0.f;
            acc[t][r] = v;
            s1p[r] = fmaf(v, a1, s1p[r]);
            s2p[r] = fmaf(v, a2, s2p[r]);
        }
    }
#pragma unroll
    for (int r = 0; r < 4; r++) {
#pragma unroll
        for (int off = 1; off < 16; off <<= 1) {
            s1p[r] += __shfl_xor(s1p[r], off, 64);
            s2p[r] += __shfl_xor(s2p[r], off, 64);
        }
    }
    if (l15 == 0) {
#pragma unroll
        for (int r = 0; r < 4; r++) {
            int rowg = row0 + w * 16 + quad * 4 + r;
            s1g[rowg] = s1p[r];
            s2g[rowg] = s2p[r];
        }
    }
    float mx = fmaxf(fmaxf(s2p[0], s2p[1]), fmaxf(s2p[2], s2p[3]));
    mx = fmaxf(mx, __shfl_xor(mx, 16, 64));
    mx = fmaxf(mx, __shfl_xor(mx, 32, 64));
    if (lane == 0) s2blk[w] = mx;
    __syncthreads();                  // all MFMA reads of wsb done; s2blk visible

    short* st = (short*)wsb;          // transpose buffer (64 rows x stride 130)
#pragma unroll
    for (int t = 0; t < 8; t++)
#pragma unroll
        for (int r = 0; r < 4; r++)
            st[(w * 16 + quad * 4 + r) * 130 + t * 16 + l15] = (short)f2bf(acc[t][r]);
    __syncthreads();
    if (tid == 0) {
        float m2 = fmaxf(fmaxf(s2blk[0], s2blk[1]), fmaxf(s2blk[2], s2blk[3]));
        atomicMax(&s2mx[layer * 8 + b], fenc(m2));
    }
    int i0 = (blk & 31) * 64;
    for (int c = tid; c < 1024; c += 256) {           // 4 t x 4 jt x 64 lanes
        int t = c >> 8, jl2 = (c >> 6) & 3, sl = c & 63;
        int d = t * 32 + (sl & 31);
        int jloc = jl2 * 16 + (sl >> 5) * 8;
        short8 o;
#pragma unroll
        for (int i = 0; i < 8; i++) o[i] = st[(jloc + i) * 130 + d];
        int jtg = (i0 >> 4) + jl2;
        *(short8*)&hP[(((size_t)(b * 4 + t) * 128 + jtg) * 64 + sl) * 8] = o;
    }
}

// ---- per layer: flash P@H via 32x32x16 MFMA, B coalesced from packed hP -----
// grid 512 x 256thr: 32-row blocks, 4 waves; wave w owns j in [w*512,(w+1)*512)
__global__ __launch_bounds__(256) void k_attn(
    const unsigned long long* __restrict__ packed,
    const unsigned short* __restrict__ hP, const float* __restrict__ s1g,
    const float* __restrict__ s2g, const unsigned* __restrict__ s2mx,
    int layer, float* __restrict__ Opart, float* __restrict__ Ppart)
{
    int blk = blockIdx.x, tid = threadIdx.x;
    int b = blk >> 6;
    int rowg0 = blk * 32;
    int w = tid >> 6, lane = tid & 63;
    int col = lane & 31, khalf = lane >> 5;

    float s1v = s1g[rowg0 + col];                // A row = lane&31
    float s2m = fdec(s2mx[layer * 8 + b]);
    float tmh = s1v + s2m;
    float mhat = fmaxf(tmh, 0.2f * tmh);         // leaky(s1 + max_b s2) >= all e

    f32x16 acc[5];
#pragma unroll
    for (int t = 0; t < 5; t++)
#pragma unroll
        for (int r = 0; r < 16; r++) acc[t][r] = 0.f;

    // constant ones B fragment: col 0 = 1.0 for all k -> row-sum in D col 0
    short8 onesf;
    {
        short v = (col == 0) ? (short)0x3F80 : (short)0;
        onesf[0]=v;onesf[1]=v;onesf[2]=v;onesf[3]=v;onesf[4]=v;onesf[5]=v;onesf[6]=v;onesf[7]=v;
    }

    const float* s2b = s2g + b * 2048;
    const unsigned short* hPb = hP + (size_t)b * 4 * 128 * 64 * 8;
    const unsigned long long* prow = packed + (size_t)(rowg0 + col) * 32;

    unsigned long long word = 0;
#pragma unroll 4
    for (int jl = 0; jl < 32; jl++) {
        int jt = w * 32 + jl;
        if ((jl & 3) == 0) word = prow[jt >> 2];
        unsigned b8 = (unsigned)(word >> ((jt & 3) * 16 + khalf * 8)) & 0xffu;
        int j0 = jt * 16 + khalf * 8;
        f32x4 sa = *(const f32x4*)&s2b[j0];
        f32x4 sb = *(const f32x4*)&s2b[j0 + 4];
        float sv[8] = {sa[0], sa[1], sa[2], sa[3], sb[0], sb[1], sb[2], sb[3]};
        unsigned rp[8];
#pragma unroll
        for (int jj = 0; jj < 8; jj++) {
            float e = s1v + sv[jj];
            e = fmaxf(e, 0.2f * e);              // leaky_relu
            float pv = __expf(e - mhat);
            // round-half-up to bf16 via +0x8000, take high 16
            rp[jj] = (b8 & (1u << jj)) ? (__float_as_uint(pv) + 0x8000u) : 0u;
        }
        uint4v pk;
        pk[0] = (rp[0] >> 16) | (rp[1] & 0xffff0000u);
        pk[1] = (rp[2] >> 16) | (rp[3] & 0xffff0000u);
        pk[2] = (rp[4] >> 16) | (rp[5] & 0xffff0000u);
        pk[3] = (rp[6] >> 16) | (rp[7] & 0xffff0000u);
        short8 af = *(short8*)&pk;
        short8 bfr[4];
#pragma unroll
        for (int t = 0; t < 4; t++)              // coalesced: 64 lanes x 16B
            bfr[t] = *(const short8*)&hPb[(((size_t)t * 128 + jt) * 64 + lane) * 8];
#pragma unroll
        for (int t = 0; t < 4; t++)
            acc[t] = __builtin_amdgcn_mfma_f32_32x32x16_bf16(af, bfr[t], acc[t], 0, 0, 0);
        acc[4] = __builtin_amdgcn_mfma_f32_32x32x16_bf16(af, onesf, acc[4], 0, 0, 0);
    }

    // write partial O and psum for this j-slice
    // C/D map (verified): col = lane&31, row = (reg&3) + 8*(reg>>2) + 4*(lane>>5)
#pragma unroll
    for (int reg = 0; reg < 16; reg++) {
        int row = (reg & 3) + 8 * (reg >> 2) + 4 * khalf;
        int rowgC = rowg0 + row;
#pragma unroll
        for (int t = 0; t < 4; t++)
            Opart[((size_t)w * 16384 + rowgC) * 128 + t * 32 + col] = acc[t][reg];
        if (col == 0) Ppart[w * 16384 + rowgC] = acc[4][reg];
    }
}

// ---- combine 4 wave-slices: x += (O0+O1+O2+O3) / (p0+p1+p2+p3) --------------
__global__ __launch_bounds__(256) void k_comb(
    const float* __restrict__ Opart, const float* __restrict__ Ppart,
    float* __restrict__ xq)
{
    int idx = blockIdx.x * 256 + threadIdx.x;    // f32x4 index, 524288 total
    int row = idx >> 5;                          // 32 f32x4 per row
    float p = Ppart[row] + Ppart[16384 + row] + Ppart[32768 + row] + Ppart[49152 + row];
    float rl = p > 0.f ? 1.0f / p : 0.f;
    // slices offset by 16384 rows * 128 = 2,097,152 floats
    f32x4 o0 = *(const f32x4*)&Opart[(size_t)idx * 4];
    f32x4 o1 = *(const f32x4*)&Opart[(size_t)idx * 4 + 2097152];
    f32x4 o2 = *(const f32x4*)&Opart[(size_t)idx * 4 + 4194304];
    f32x4 o3 = *(const f32x4*)&Opart[(size_t)idx * 4 + 6291456];
    f32x4 xv = *(const f32x4*)&xq[idx * 4];
#pragma unroll
    for (int k = 0; k < 4; k++) xv[k] += (o0[k] + o1[k] + o2[k] + o3[k]) * rl;
    *(f32x4*)&xq[idx * 4] = xv;
}

extern "C" void kernel_launch(void* const* d_in, const int* in_sizes, int n_in,
                              void* d_out, int out_size, void* d_ws, size_t ws_size,
                              hipStream_t stream) {
    // adj = largest input; among the rest (excluding x = d_in[0]): W > attn_a > bg
    const void* px = d_in[0];
    int ia = 1; long amax = -1;
    for (int i = 1; i < n_in; i++)
        if ((long)in_sizes[i] > amax) { amax = in_sizes[i]; ia = i; }
    int rem[8]; int m = 0;
    for (int i = 1; i < n_in && m < 8; i++) if (i != ia) rem[m++] = i;
    for (int i = 0; i < m; i++)
        for (int j = i + 1; j < m; j++)
            if (in_sizes[rem[j]] > in_sizes[rem[i]]) { int t = rem[i]; rem[i] = rem[j]; rem[j] = t; }
    const int*   padj = (const int*)((n_in > 1) ? d_in[ia] : d_in[0]);
    const float* pW = (const float*)((m > 0) ? d_in[rem[0]] : d_in[0]);
    const float* pa = (const float*)((m > 1) ? d_in[rem[1]] : d_in[0]);
    const float* pb = (const float*)((m > 2) ? d_in[rem[2]] : d_in[0]);

    float* xq = (float*)d_out;                        // running fp32 x = output
    char* ws = (char*)d_ws;
    unsigned long long* packed = (unsigned long long*)ws;   // 4 MiB bitmask
    unsigned short* hP = (unsigned short*)(ws + 4194304);   // 4 MiB packed bf16 H
    float* s1 = (float*)(ws + 8388608);                     // 64 KiB
    float* s2 = (float*)(ws + 8454144);                     // 64 KiB
    unsigned* s2mx = (unsigned*)(ws + 8519680);             // 24 slots
    unsigned short* wTb = (unsigned short*)(ws + 8519808);  // 96 KiB bf16 W^T
    float* Opart = (float*)(ws + 16777216);                 // 32 MiB (4 slices)
    float* Ppart = (float*)(ws + 50331648);                 // 256 KiB (4 slices)

    k_init<<<2241, 256, 0, stream>>>((const float*)px, pW, xq, wTb, s2mx);
    k_pack<<<2048, 256, 0, stream>>>(padj, packed);
    for (int l = 0; l < 3; l++) {
        k_h<<<256, 256, 0, stream>>>(xq, wTb, pb, pa, l, hP, s1, s2, s2mx);
        k_attn<<<512, 256, 0, stream>>>(packed, hP, s1, s2, s2mx, l, Opart, Ppart);
        k_comb<<<2048, 256, 0, stream>>>(Opart, Ppart, xq);
    }
}

// Round 17
// 344.651 us; speedup vs baseline: 1.1452x; 1.0543x over previous
//
#include <hip/hip_runtime.h>
#include <stdint.h>

typedef __attribute__((ext_vector_type(8))) short short8;
typedef __attribute__((ext_vector_type(4))) float f32x4;
typedef __attribute__((ext_vector_type(16))) float f32x16;
typedef __attribute__((ext_vector_type(4))) unsigned uint4v;

__device__ __forceinline__ unsigned short f2bf(float f) {
    unsigned u = __float_as_uint(f);
    unsigned r = u + 0x7fffu + ((u >> 16) & 1u);   // RNE
    return (unsigned short)(r >> 16);
}
// monotone float<->uint encoding for atomicMax on floats
__device__ __forceinline__ unsigned fenc(float f) {
    unsigned u = __float_as_uint(f);
    return (u & 0x80000000u) ? ~u : (u | 0x80000000u);
}
__device__ __forceinline__ float fdec(unsigned e) {
    unsigned u = (e & 0x80000000u) ? (e & 0x7fffffffu) : ~e;
    return __uint_as_float(u);
}

// ---- fused setup: pack adj, copy x, W -> bf16 W^T, init s2 max slots --------
__global__ __launch_bounds__(256) void k_setup(
    const float* __restrict__ xin, const float* __restrict__ Wf,
    const int* __restrict__ adj, float* __restrict__ xq,
    unsigned short* __restrict__ wTb, unsigned* __restrict__ s2mx,
    unsigned long long* __restrict__ packed)
{
    int blk = blockIdx.x, tid = threadIdx.x;
    if (blk < 2048) {                                 // pack adj -> bitmask
        int w = (blk * 256 + tid) >> 6;               // global wave id, 8192 waves
        int lane = tid & 63;
        for (int k = 0; k < 64; k++) {
            int q = w * 64 + k;                       // word index 0..524287
            int row = q >> 5, wd = q & 31;
            int v = adj[row * 2048 + wd * 64 + lane];
            unsigned long long m = __ballot(v > 0);
            if (lane == 0) packed[q] = m;
        }
    } else if (blk < 4096) {                          // x -> running fp32 x
        int e0 = ((blk - 2048) * 256 + tid) * 4;
        *(f32x4*)(xq + e0) = *(const f32x4*)(xin + e0);
    } else if (blk < 4288) {                          // W -> bf16 W^T
        int c = (blk - 4096) * 256 + tid;             // < 49152
        int l = c >> 14, rem = c & 16383, n = rem >> 7, k = rem & 127;
        wTb[c] = f2bf(Wf[l * 16384 + k * 128 + n]);   // wTb[l][n][k] = W[l][k][n]
    } else if (tid < 24) {
        s2mx[tid] = fenc(-3e38f);
    }
}

// ---- per layer: h = relu(x@W+b) via bf16 MFMA; s1,s2; batch max; hP packed --
// hP[b][t][jt][lane][8]: element = h[j = jt*16 + (lane>>5)*8 + i][d = t*32 + (lane&31)]
__global__ __launch_bounds__(256) void k_h(
    const float* __restrict__ xq, const unsigned short* __restrict__ wTb,
    const float* __restrict__ bF, const float* __restrict__ aF, int layer,
    unsigned short* __restrict__ hP, float* __restrict__ s1g,
    float* __restrict__ s2g, unsigned* __restrict__ s2mx)
{
    __shared__ short xs[64 * 136];    // 17.4 KB, x tile bf16
    __shared__ short wsb[128 * 136];  // 34.8 KB, W^T tile bf16; reused for transpose
    __shared__ float s2blk[4];
    int blk = blockIdx.x, tid = threadIdx.x;
    int row0 = blk * 64, b = blk >> 5;
    int w = tid >> 6, lane = tid & 63, quad = lane >> 4, l15 = lane & 15;

    for (int c = tid; c < 1024; c += 256) {           // x: 64 rows x 128 k
        int r = c >> 4, kg = c & 15;
        const float* src = &xq[(row0 + r) * 128 + kg * 8];
        f32x4 v0 = *(const f32x4*)src;
        f32x4 v1 = *(const f32x4*)(src + 4);
        short8 o;
        o[0] = (short)f2bf(v0[0]); o[1] = (short)f2bf(v0[1]);
        o[2] = (short)f2bf(v0[2]); o[3] = (short)f2bf(v0[3]);
        o[4] = (short)f2bf(v1[0]); o[5] = (short)f2bf(v1[1]);
        o[6] = (short)f2bf(v1[2]); o[7] = (short)f2bf(v1[3]);
        *(short8*)&xs[r * 136 + kg * 8] = o;
    }
    const unsigned short* wl = wTb + layer * 16384;
    for (int c = tid; c < 2048; c += 256) {           // W^T: 128 n x 128 k
        int n = c >> 4, kg = c & 15;
        *(short8*)&wsb[n * 136 + kg * 8] = *(const short8*)&wl[n * 128 + kg * 8];
    }
    __syncthreads();

    f32x4 acc[8];
#pragma unroll
    for (int t = 0; t < 8; t++) acc[t] = {0.f, 0.f, 0.f, 0.f};
#pragma unroll
    for (int ks = 0; ks < 4; ks++) {
        short8 af = *(const short8*)&xs[(w * 16 + l15) * 136 + ks * 32 + quad * 8];
#pragma unroll
        for (int t = 0; t < 8; t++) {
            short8 bf = *(const short8*)&wsb[(t * 16 + l15) * 136 + ks * 32 + quad * 8];
            acc[t] = __builtin_amdgcn_mfma_f32_16x16x32_bf16(af, bf, acc[t], 0, 0, 0);
        }
    }

    // epilogue: bias+relu, s1/s2 row dots (reduce over l15 lanes via shfl)
    float s1p[4] = {0.f, 0.f, 0.f, 0.f}, s2p[4] = {0.f, 0.f, 0.f, 0.f};
#pragma unroll
    for (int t = 0; t < 8; t++) {
        int colg = t * 16 + l15;
        float bgf = bF[layer * 128 + colg];
        float a1 = aF[layer * 256 + colg];
        float a2 = aF[layer * 256 + 128 + colg];
#pragma unroll
        for (int r = 0; r < 4; r++) {
            float v = acc[t][r] + bgf;
            v = v > 0.f ? v : 0.f;
            acc[t][r] = v;
            s1p[r] = fmaf(v, a1, s1p[r]);
            s2p[r] = fmaf(v, a2, s2p[r]);
        }
    }
#pragma unroll
    for (int r = 0; r < 4; r++) {
#pragma unroll
        for (int off = 1; off < 16; off <<= 1) {
            s1p[r] += __shfl_xor(s1p[r], off, 64);
            s2p[r] += __shfl_xor(s2p[r], off, 64);
        }
    }
    if (l15 == 0) {
#pragma unroll
        for (int r = 0; r < 4; r++) {
            int rowg = row0 + w * 16 + quad * 4 + r;
            s1g[rowg] = s1p[r];
            s2g[rowg] = s2p[r];
        }
    }
    float mx = fmaxf(fmaxf(s2p[0], s2p[1]), fmaxf(s2p[2], s2p[3]));
    mx = fmaxf(mx, __shfl_xor(mx, 16, 64));
    mx = fmaxf(mx, __shfl_xor(mx, 32, 64));
    if (lane == 0) s2blk[w] = mx;
    __syncthreads();                  // all MFMA reads of wsb done; s2blk visible

    short* st = (short*)wsb;          // transpose buffer (64 rows x stride 130)
#pragma unroll
    for (int t = 0; t < 8; t++)
#pragma unroll
        for (int r = 0; r < 4; r++)
            st[(w * 16 + quad * 4 + r) * 130 + t * 16 + l15] = (short)f2bf(acc[t][r]);
    __syncthreads();
    if (tid == 0) {
        float m2 = fmaxf(fmaxf(s2blk[0], s2blk[1]), fmaxf(s2blk[2], s2blk[3]));
        atomicMax(&s2mx[layer * 8 + b], fenc(m2));
    }
    int i0 = (blk & 31) * 64;
    for (int c = tid; c < 1024; c += 256) {           // 4 t x 4 jt x 64 lanes
        int t = c >> 8, jl2 = (c >> 6) & 3, sl = c & 63;
        int d = t * 32 + (sl & 31);
        int jloc = jl2 * 16 + (sl >> 5) * 8;
        short8 o;
#pragma unroll
        for (int i = 0; i < 8; i++) o[i] = st[(jloc + i) * 130 + d];
        int jtg = (i0 >> 4) + jl2;
        *(short8*)&hP[(((size_t)(b * 4 + t) * 128 + jtg) * 64 + sl) * 8] = o;
    }
}

// ---- per layer: flash P@H via 32x32x16 MFMA; block owns ALL j for 32 rows ---
// grid 512 x 256thr: 4 waves interleave jt = w + 4*jl, jl=0..31 (ALL 128 jt —
// R16 bug: jl<8 covered only 1/4 of j); one LDS reduction; x updated in place.
__global__ __launch_bounds__(256) void k_attn(
    const unsigned long long* __restrict__ packed,
    const unsigned short* __restrict__ hP, const float* __restrict__ s1g,
    const float* __restrict__ s2g, const unsigned* __restrict__ s2mx,
    int layer, float* __restrict__ xq)
{
    __shared__ float red[3 * 32 * 128];          // 48 KB wave partials
    __shared__ float red_p[4 * 32];              // psum partials
    int blk = blockIdx.x, tid = threadIdx.x;
    int b = blk >> 6;
    int rowg0 = blk * 32;
    int w = tid >> 6, lane = tid & 63;
    int col = lane & 31, khalf = lane >> 5;

    float s1v = s1g[rowg0 + col];                // A row = lane&31
    float s2m = fdec(s2mx[layer * 8 + b]);
    float tmh = s1v + s2m;
    float mhat = fmaxf(tmh, 0.2f * tmh);         // leaky(s1 + max_b s2) >= all e

    f32x16 acc[5];
#pragma unroll
    for (int t = 0; t < 5; t++)
#pragma unroll
        for (int r = 0; r < 16; r++) acc[t][r] = 0.f;

    // constant ones B fragment: col 0 = 1.0 for all k -> row-sum in D col 0
    short8 onesf;
    {
        short v = (col == 0) ? (short)0x3F80 : (short)0;
        onesf[0]=v;onesf[1]=v;onesf[2]=v;onesf[3]=v;onesf[4]=v;onesf[5]=v;onesf[6]=v;onesf[7]=v;
    }

    const float* s2b = s2g + b * 2048;
    const unsigned short* hPb = hP + (size_t)b * 4 * 128 * 64 * 8;
    const unsigned long long* prow = packed + (size_t)(rowg0 + col) * 32;

    for (int jl = 0; jl < 32; jl++) {            // ALL 32 words -> 128 jt/block
        int jt = w + jl * 4;                     // jt>>2 == jl, jt&3 == w
        unsigned long long word = prow[jl];
        unsigned b8 = (unsigned)(word >> (w * 16 + khalf * 8)) & 0xffu;
        int j0 = jt * 16 + khalf * 8;
        f32x4 sa = *(const f32x4*)&s2b[j0];
        f32x4 sb = *(const f32x4*)&s2b[j0 + 4];
        float sv[8] = {sa[0], sa[1], sa[2], sa[3], sb[0], sb[1], sb[2], sb[3]};
        unsigned rp[8];
#pragma unroll
        for (int jj = 0; jj < 8; jj++) {
            float e = s1v + sv[jj];
            e = fmaxf(e, 0.2f * e);              // leaky_relu
            float pv = __expf(e - mhat);
            // round-half-up to bf16 via +0x8000, take high 16
            rp[jj] = (b8 & (1u << jj)) ? (__float_as_uint(pv) + 0x8000u) : 0u;
        }
        uint4v pk;
        pk[0] = (rp[0] >> 16) | (rp[1] & 0xffff0000u);
        pk[1] = (rp[2] >> 16) | (rp[3] & 0xffff0000u);
        pk[2] = (rp[4] >> 16) | (rp[5] & 0xffff0000u);
        pk[3] = (rp[6] >> 16) | (rp[7] & 0xffff0000u);
        short8 af = *(short8*)&pk;
        short8 bfr[4];
#pragma unroll
        for (int t = 0; t < 4; t++)              // coalesced: 64 lanes x 16B
            bfr[t] = *(const short8*)&hPb[(((size_t)t * 128 + jt) * 64 + lane) * 8];
#pragma unroll
        for (int t = 0; t < 4; t++)
            acc[t] = __builtin_amdgcn_mfma_f32_32x32x16_bf16(af, bfr[t], acc[t], 0, 0, 0);
        acc[4] = __builtin_amdgcn_mfma_f32_32x32x16_bf16(af, onesf, acc[4], 0, 0, 0);
    }

    // reduce 4 wave partials in LDS; wave 0 normalizes and updates x in place.
    // C/D map (verified): col = lane&31, row = (reg&3) + 8*(reg>>2) + 4*(lane>>5)
#pragma unroll
    for (int reg = 0; reg < 16; reg++) {
        int row = (reg & 3) + 8 * (reg >> 2) + 4 * khalf;
        if (w > 0) {
#pragma unroll
            for (int t = 0; t < 4; t++)
                red[(w - 1) * 4096 + row * 128 + t * 32 + col] = acc[t][reg];
        }
        if (col == 0) red_p[w * 32 + row] = acc[4][reg];   // psum lives in col 0
    }
    __syncthreads();
    if (w == 0) {
#pragma unroll
        for (int reg = 0; reg < 16; reg++) {
            int row = (reg & 3) + 8 * (reg >> 2) + 4 * khalf;
            float p = red_p[row] + red_p[32 + row] + red_p[64 + row] + red_p[96 + row];
            float rl = p > 0.f ? 1.0f / p : 0.f;
#pragma unroll
            for (int t = 0; t < 4; t++) {
                int cidx = row * 128 + t * 32 + col;
                float o = acc[t][reg] + red[cidx] + red[4096 + cidx] + red[8192 + cidx];
                xq[(rowg0 + row) * 128 + t * 32 + col] += o * rl;
            }
        }
    }
}

extern "C" void kernel_launch(void* const* d_in, const int* in_sizes, int n_in,
                              void* d_out, int out_size, void* d_ws, size_t ws_size,
                              hipStream_t stream) {
    // adj = largest input; among the rest (excluding x = d_in[0]): W > attn_a > bg
    const void* px = d_in[0];
    int ia = 1; long amax = -1;
    for (int i = 1; i < n_in; i++)
        if ((long)in_sizes[i] > amax) { amax = in_sizes[i]; ia = i; }
    int rem[8]; int m = 0;
    for (int i = 1; i < n_in && m < 8; i++) if (i != ia) rem[m++] = i;
    for (int i = 0; i < m; i++)
        for (int j = i + 1; j < m; j++)
            if (in_sizes[rem[j]] > in_sizes[rem[i]]) { int t = rem[i]; rem[i] = rem[j]; rem[j] = t; }
    const int*   padj = (const int*)((n_in > 1) ? d_in[ia] : d_in[0]);
    const float* pW = (const float*)((m > 0) ? d_in[rem[0]] : d_in[0]);
    const float* pa = (const float*)((m > 1) ? d_in[rem[1]] : d_in[0]);
    const float* pb = (const float*)((m > 2) ? d_in[rem[2]] : d_in[0]);

    float* xq = (float*)d_out;                        // running fp32 x = output
    char* ws = (char*)d_ws;
    unsigned long long* packed = (unsigned long long*)ws;   // 4 MiB bitmask
    unsigned short* hP = (unsigned short*)(ws + 4194304);   // 4 MiB packed bf16 H
    float* s1 = (float*)(ws + 8388608);                     // 64 KiB
    float* s2 = (float*)(ws + 8454144);                     // 64 KiB
    unsigned* s2mx = (unsigned*)(ws + 8519680);             // 24 slots
    unsigned short* wTb = (unsigned short*)(ws + 8519808);  // 96 KiB bf16 W^T

    k_setup<<<4289, 256, 0, stream>>>((const float*)px, pW, padj, xq, wTb, s2mx, packed);
    for (int l = 0; l < 3; l++) {
        k_h<<<256, 256, 0, stream>>>(xq, wTb, pb, pa, l, hP, s1, s2, s2mx);
        k_attn<<<512, 256, 0, stream>>>(packed, hP, s1, s2, s2mx, l, xq);
    }
}